// Round 12
// baseline (404.942 us; speedup 1.0000x reference)
//
#include <hip/hip_runtime.h>
#include <math.h>

#define BB 32
#define TT 512
#define EE 128
#define NHH 16
#define HDD 8
#define G3 384
#define NGRU 6
#define NATT 192

typedef __attribute__((ext_vector_type(2))) _Float16 half2_t;
typedef __attribute__((ext_vector_type(4))) _Float16 half4_t;
typedef __attribute__((ext_vector_type(8))) _Float16 half8_t;
typedef __attribute__((ext_vector_type(4))) float f32x4;

__device__ __forceinline__ float sigmoidf_(float x) {
  return __builtin_amdgcn_rcpf(1.0f + __expf(-x));
}

__device__ __forceinline__ float exp2_(float x) {
#if __has_builtin(__builtin_amdgcn_exp2f)
  return __builtin_amdgcn_exp2f(x);
#else
  return exp2f(x);
#endif
}

// load 8 consecutive f32 and convert to a f16 MFMA fragment
__device__ __forceinline__ half8_t ldfrag(const float* p) {
  float4 f0 = *(const float4*)p;
  float4 f1 = *(const float4*)(p + 4);
  half8_t r;
  r[0] = (_Float16)f0.x; r[1] = (_Float16)f0.y;
  r[2] = (_Float16)f0.z; r[3] = (_Float16)f0.w;
  r[4] = (_Float16)f1.x; r[5] = (_Float16)f1.y;
  r[6] = (_Float16)f1.z; r[7] = (_Float16)f1.w;
  return r;
}

// K0: fold lookup/posres/attn_in into coef[5][384] and per-head 5x5 M (scaled).
__global__ __launch_bounds__(512) void coef_kernel(
    const float* __restrict__ attn_in_w, const float* __restrict__ attn_in_b,
    const float* __restrict__ lookup_w, const float* __restrict__ lookup_b,
    const float* __restrict__ posres_w, const float* __restrict__ posres_b,
    float* __restrict__ coef, float* __restrict__ Mh) {
  int j = threadIdx.x;
  __shared__ float cL[5][G3];
  if (j < G3) {
    float u0 = 0.f, u1 = 0.f, cs = 0.f, cc = 0.f, cb = 0.f;
    const float* wrow = attn_in_w + j * EE;
    for (int e = 0; e < EE; ++e) {
      float w = wrow[e];
      float pw0 = posres_w[e * 2], pw1 = posres_w[e * 2 + 1];
      u0 += w * (lookup_w[e * 2] + pw0);
      u1 += w * (lookup_w[e * 2 + 1] + pw1);
      cs += w * pw0;
      cc += w * pw1;
      cb += w * (lookup_b[e] + posres_b[e]);
    }
    cb += attn_in_b[j];
    coef[0 * G3 + j] = u0;
    coef[1 * G3 + j] = u1;
    coef[2 * G3 + j] = cs;
    coef[3 * G3 + j] = cc;
    coef[4 * G3 + j] = cb;
    cL[0][j] = u0;
    cL[1][j] = u1;
    cL[2][j] = cs;
    cL[3][j] = cc;
    cL[4][j] = cb;
  }
  __syncthreads();
  if (j < NHH * 25) {
    int h = j / 25;
    int ij = j % 25;
    int i = ij / 5, jj = ij % 5;
    const float SCL = 0.35355339059327373f * 1.4426950408889634f;
    float acc = 0.f;
#pragma unroll
    for (int d = 0; d < HDD; ++d)
      acc += cL[i][h * HDD + d] * cL[jj][EE + h * HDD + d];
    Mh[h * 25 + ij] = acc * SCL;
  }
}

// Merged kernel: blocks [0,6) = MFMA-GRU (one per (s, half-batch of 16));
// blocks [6, 6+192) = attention (wave = head).
__global__ __launch_bounds__(512) void fused_kernel(
    const float* __restrict__ in0, const float* __restrict__ in1,
    const float* __restrict__ in2, const int* __restrict__ len0,
    const int* __restrict__ len1, const int* __restrict__ len2,
    const float* __restrict__ w_ih, const float* __restrict__ w_hh,
    const float* __restrict__ b_ih, const float* __restrict__ b_hh,
    const float* __restrict__ coef, const float* __restrict__ Mh,
    float* __restrict__ coor_embs, float* __restrict__ ohat) {
  __shared__ __align__(16) unsigned char smem[41472];
  int tid = threadIdx.x;
  if (blockIdx.x < NGRU) {
    // ---------------- GRU via MFMA: G(384x16) = W_hh @ H(128x16) -------------
    int blk = blockIdx.x;       // s*2 + hb
    int s = blk >> 1;
    int hb = blk & 1;
    const float* inp = (s == 0) ? in0 : (s == 1) ? in1 : in2;
    const int* lenp = (s == 0) ? len0 : (s == 1) ? len1 : len2;
    int w = tid >> 6;   // wave 0..7 -> row-tile rows [16w,16w+16)
    int l = tid & 63;
    int c = l & 15;     // A row within tile / B col (batch) / C col
    int q = l >> 4;     // quadrant: A/B k-offset 8q ; C rows 4q..4q+3

    _Float16* Ht = (_Float16*)smem;             // [2][16][136] f16
    half2_t* xst = (half2_t*)(smem + 8704);     // [512][16] (x0,x1)

    // stage x (coalesced reads over t)
    for (int idx = tid; idx < 16 * TT; idx += 512) {
      int t = idx & 511;
      int bl = idx >> 9;
      float4 v = *(const float4*)(inp + ((size_t)(hb * 16 + bl) * TT + t) * 4);
      half2_t xv;
      xv[0] = (_Float16)v.x;
      xv[1] = (_Float16)v.y;
      xst[t * 16 + bl] = xv;
    }
    // zero Ht buf0
    for (int idx = tid; idx < 16 * 136; idx += 512) Ht[idx] = (_Float16)0.0f;

    int lenc = lenp[hb * 16 + c];
    int maxlen = lenc;
#pragma unroll
    for (int off = 1; off < 16; off <<= 1) {
      int o = __shfl_xor(maxlen, off, 64);
      maxlen = maxlen > o ? maxlen : o;
    }

    // A fragments (weights), resident: 12 x half8 = 48 VGPR
    const float* pR = w_hh + ((size_t)(0 + 16 * w + c)) * EE + 8 * q;
    const float* pZ = w_hh + ((size_t)(128 + 16 * w + c)) * EE + 8 * q;
    const float* pN = w_hh + ((size_t)(256 + 16 * w + c)) * EE + 8 * q;
    half8_t aR0 = ldfrag(pR), aR1 = ldfrag(pR + 32), aR2 = ldfrag(pR + 64), aR3 = ldfrag(pR + 96);
    half8_t aZ0 = ldfrag(pZ), aZ1 = ldfrag(pZ + 32), aZ2 = ldfrag(pZ + 64), aZ3 = ldfrag(pZ + 96);
    half8_t aN0 = ldfrag(pN), aN1 = ldfrag(pN + 32), aN2 = ldfrag(pN + 64), aN3 = ldfrag(pN + 96);

    // per-lane row constants (rows e0..e0+3)
    int e0 = 16 * w + 4 * q;
    float br_[4], bz_[4], bn_[4], bhn_[4];
    float wir0_[4], wir1_[4], wiz0_[4], wiz1_[4], win0_[4], win1_[4];
#pragma unroll
    for (int rr = 0; rr < 4; ++rr) {
      int er = e0 + rr;
      br_[rr] = b_ih[er] + b_hh[er];
      bz_[rr] = b_ih[128 + er] + b_hh[128 + er];
      bn_[rr] = b_ih[256 + er];
      bhn_[rr] = b_hh[256 + er];
      wir0_[rr] = w_ih[er * 2];
      wir1_[rr] = w_ih[er * 2 + 1];
      wiz0_[rr] = w_ih[(128 + er) * 2];
      wiz1_[rr] = w_ih[(128 + er) * 2 + 1];
      win0_[rr] = w_ih[(256 + er) * 2];
      win1_[rr] = w_ih[(256 + er) * 2 + 1];
    }

    float hold0 = 0.f, hold1 = 0.f, hold2 = 0.f, hold3 = 0.f;
    float hs0 = 0.f, hs1 = 0.f, hs2 = 0.f, hs3 = 0.f;
    __syncthreads();

    int cur = 0;
#pragma unroll 1
    for (int t = 0; t < maxlen; ++t) {
      const _Float16* hrow = Ht + cur * 2176 + c * 136 + 8 * q;
      half8_t b0 = *(const half8_t*)(hrow);
      half8_t b1 = *(const half8_t*)(hrow + 32);
      half8_t b2 = *(const half8_t*)(hrow + 64);
      half8_t b3 = *(const half8_t*)(hrow + 96);

      f32x4 aR = {0.f, 0.f, 0.f, 0.f};
      f32x4 aZ = {0.f, 0.f, 0.f, 0.f};
      f32x4 aN = {0.f, 0.f, 0.f, 0.f};
      aR = __builtin_amdgcn_mfma_f32_16x16x32_f16(aR0, b0, aR, 0, 0, 0);
      aZ = __builtin_amdgcn_mfma_f32_16x16x32_f16(aZ0, b0, aZ, 0, 0, 0);
      aN = __builtin_amdgcn_mfma_f32_16x16x32_f16(aN0, b0, aN, 0, 0, 0);
      aR = __builtin_amdgcn_mfma_f32_16x16x32_f16(aR1, b1, aR, 0, 0, 0);
      aZ = __builtin_amdgcn_mfma_f32_16x16x32_f16(aZ1, b1, aZ, 0, 0, 0);
      aN = __builtin_amdgcn_mfma_f32_16x16x32_f16(aN1, b1, aN, 0, 0, 0);
      aR = __builtin_amdgcn_mfma_f32_16x16x32_f16(aR2, b2, aR, 0, 0, 0);
      aZ = __builtin_amdgcn_mfma_f32_16x16x32_f16(aZ2, b2, aZ, 0, 0, 0);
      aN = __builtin_amdgcn_mfma_f32_16x16x32_f16(aN2, b2, aN, 0, 0, 0);
      aR = __builtin_amdgcn_mfma_f32_16x16x32_f16(aR3, b3, aR, 0, 0, 0);
      aZ = __builtin_amdgcn_mfma_f32_16x16x32_f16(aZ3, b3, aZ, 0, 0, 0);
      aN = __builtin_amdgcn_mfma_f32_16x16x32_f16(aN3, b3, aN, 0, 0, 0);

      half2_t xv = xst[t * 16 + c];
      float x0 = (float)xv[0], x1 = (float)xv[1];

      float rg0 = sigmoidf_(br_[0] + wir0_[0] * x0 + wir1_[0] * x1 + aR[0]);
      float zg0 = sigmoidf_(bz_[0] + wiz0_[0] * x0 + wiz1_[0] * x1 + aZ[0]);
      float tg0 = bn_[0] + win0_[0] * x0 + win1_[0] * x1 + rg0 * (bhn_[0] + aN[0]);
      float ng0 = 1.0f - 2.0f * __builtin_amdgcn_rcpf(__expf(2.0f * tg0) + 1.0f);
      hold0 = ng0 + zg0 * (hold0 - ng0);

      float rg1 = sigmoidf_(br_[1] + wir0_[1] * x0 + wir1_[1] * x1 + aR[1]);
      float zg1 = sigmoidf_(bz_[1] + wiz0_[1] * x0 + wiz1_[1] * x1 + aZ[1]);
      float tg1 = bn_[1] + win0_[1] * x0 + win1_[1] * x1 + rg1 * (bhn_[1] + aN[1]);
      float ng1 = 1.0f - 2.0f * __builtin_amdgcn_rcpf(__expf(2.0f * tg1) + 1.0f);
      hold1 = ng1 + zg1 * (hold1 - ng1);

      float rg2 = sigmoidf_(br_[2] + wir0_[2] * x0 + wir1_[2] * x1 + aR[2]);
      float zg2 = sigmoidf_(bz_[2] + wiz0_[2] * x0 + wiz1_[2] * x1 + aZ[2]);
      float tg2 = bn_[2] + win0_[2] * x0 + win1_[2] * x1 + rg2 * (bhn_[2] + aN[2]);
      float ng2 = 1.0f - 2.0f * __builtin_amdgcn_rcpf(__expf(2.0f * tg2) + 1.0f);
      hold2 = ng2 + zg2 * (hold2 - ng2);

      float rg3 = sigmoidf_(br_[3] + wir0_[3] * x0 + wir1_[3] * x1 + aR[3]);
      float zg3 = sigmoidf_(bz_[3] + wiz0_[3] * x0 + wiz1_[3] * x1 + aZ[3]);
      float tg3 = bn_[3] + win0_[3] * x0 + win1_[3] * x1 + rg3 * (bhn_[3] + aN[3]);
      float ng3 = 1.0f - 2.0f * __builtin_amdgcn_rcpf(__expf(2.0f * tg3) + 1.0f);
      hold3 = ng3 + zg3 * (hold3 - ng3);

      if (t == lenc - 1) { hs0 = hold0; hs1 = hold1; hs2 = hold2; hs3 = hold3; }

      half4_t hp;
      hp[0] = (_Float16)hold0;
      hp[1] = (_Float16)hold1;
      hp[2] = (_Float16)hold2;
      hp[3] = (_Float16)hold3;
      *(half4_t*)(Ht + (cur ^ 1) * 2176 + c * 136 + e0) = hp;
      __syncthreads();
      cur ^= 1;
    }
    float4 o;
    o.x = hs0; o.y = hs1; o.z = hs2; o.w = hs3;
    *(float4*)(coor_embs + ((size_t)(s * 32 + hb * 16 + c)) * EE + e0) = o;
  } else {
    // ---------------- Attention (rank-5, q-register-tiled, wave=head) --------
    int a = blockIdx.x - NGRU;  // 0..191: (s, b, head-group)
    int s = a / 64;
    int rem = a - s * 64;
    int b = rem >> 1;
    int hg = rem & 1;
    const float* inp = (s == 0) ? in0 : (s == 1) ? in1 : in2;
    int wave = tid >> 6;
    int lane = tid & 63;
    int h = hg * 8 + wave;

    float4* phiL = (float4*)smem;  // [512]

    {
      int t = tid;
      float ft = (float)t;
      float st = sinf(ft);
      float ct = cosf(ft);
      float4 g = *(const float4*)(inp + ((size_t)b * TT + t) * 4);
      phiL[t] = make_float4(g.z, g.w, st, ct);
    }

    float M[25];
#pragma unroll
    for (int i = 0; i < 25; ++i) M[i] = Mh[h * 25 + i];
    __syncthreads();

    float4 p[8];
#pragma unroll
    for (int j = 0; j < 8; ++j) p[j] = phiL[lane + 64 * j];

    float Z[8];
    float N0[8], N1[8], N2[8], N3[8];
#pragma unroll
    for (int j = 0; j < 8; ++j) {
      Z[j] = 0.f; N0[j] = 0.f; N1[j] = 0.f; N2[j] = 0.f; N3[j] = 0.f;
    }

#pragma unroll 1
    for (int k = 0; k < TT; ++k) {
      float4 f = phiL[k];
      float m0 = fmaf(M[0], f.x, fmaf(M[1], f.y, fmaf(M[2], f.z, fmaf(M[3], f.w, M[4]))));
      float m1 = fmaf(M[5], f.x, fmaf(M[6], f.y, fmaf(M[7], f.z, fmaf(M[8], f.w, M[9]))));
      float m2 = fmaf(M[10], f.x, fmaf(M[11], f.y, fmaf(M[12], f.z, fmaf(M[13], f.w, M[14]))));
      float m3 = fmaf(M[15], f.x, fmaf(M[16], f.y, fmaf(M[17], f.z, fmaf(M[18], f.w, M[19]))));
      float m4 = fmaf(M[20], f.x, fmaf(M[21], f.y, fmaf(M[22], f.z, fmaf(M[23], f.w, M[24]))));
#pragma unroll
      for (int j = 0; j < 8; ++j) {
        float e0 = exp2_(fmaf(p[j].x, m0, fmaf(p[j].y, m1, fmaf(p[j].z, m2, fmaf(p[j].w, m3, m4)))));
        Z[j] += e0;
        N0[j] = fmaf(e0, f.x, N0[j]);
        N1[j] = fmaf(e0, f.y, N1[j]);
        N2[j] = fmaf(e0, f.z, N2[j]);
        N3[j] = fmaf(e0, f.w, N3[j]);
      }
    }

    float od0 = 0.f, od1 = 0.f, od2 = 0.f, od3 = 0.f;
#pragma unroll
    for (int j = 0; j < 8; ++j) {
      float rz = __builtin_amdgcn_rcpf(Z[j] * (float)TT);
      od0 = fmaf(N0[j], rz, od0);
      od1 = fmaf(N1[j], rz, od1);
      od2 = fmaf(N2[j], rz, od2);
      od3 = fmaf(N3[j], rz, od3);
    }
#pragma unroll
    for (int off = 32; off >= 1; off >>= 1) {
      od0 += __shfl_xor(od0, off, 64);
      od1 += __shfl_xor(od1, off, 64);
      od2 += __shfl_xor(od2, off, 64);
      od3 += __shfl_xor(od3, off, 64);
    }
    if (lane < HDD) {
      int jv = 2 * EE + h * HDD + lane;
      float o = coef[jv] * od0 + coef[G3 + jv] * od1 + coef[2 * G3 + jv] * od2 +
                coef[3 * G3 + jv] * od3 + coef[4 * G3 + jv];  // phi4 == 1 exactly
      int abk = s * 512 + b * 16 + h;
      ohat[(size_t)abk * HDD + lane] = o;
    }
  }
}

// K3: grid_emb = ohat @ out_w.T + out_b ; out = gamma*coor + (1-gamma)*grid
__global__ __launch_bounds__(128) void finalize_kernel(
    const float* __restrict__ attn_out_w, const float* __restrict__ attn_out_b,
    const float* __restrict__ ohat, const float* __restrict__ coor_embs,
    const float* __restrict__ gamma_p, float* __restrict__ out) {
  int blk = blockIdx.x;  // s*32 + b
  int e = threadIdx.x;
  __shared__ float ov[EE];
  ov[e] = ohat[(size_t)blk * EE + e];
  __syncthreads();
  float acc = attn_out_b[e];
  const float* wrow = attn_out_w + (size_t)e * EE;
#pragma unroll 8
  for (int f = 0; f < EE; ++f) acc += wrow[f] * ov[f];
  float g = gamma_p[0];
  out[(size_t)blk * EE + e] = g * coor_embs[(size_t)blk * EE + e] + (1.0f - g) * acc;
}

// K4: pos/neg distances from the embeddings already in d_out
__global__ void dist_kernel(float* __restrict__ out) {
  int i = threadIdx.x;  // 64 threads
  int b = i & 31;
  int neg = i >> 5;
  const float* a = out + (size_t)b * EE;
  const float* x = out + (size_t)(1 + neg) * BB * EE + (size_t)b * EE;
  float sum = 0.f;
  for (int e = 0; e < EE; ++e) {
    float d = a[e] - x[e] + 1e-6f;
    sum += d * d;
  }
  out[3 * BB * EE + neg * BB + b] = expf(-sqrtf(sum));
}

extern "C" void kernel_launch(void* const* d_in, const int* in_sizes, int n_in,
                              void* d_out, int out_size, void* d_ws, size_t ws_size,
                              hipStream_t stream) {
  const float* a_in = (const float*)d_in[0];
  const float* p_in = (const float*)d_in[1];
  const float* ng_in = (const float*)d_in[2];
  const int* a_len = (const int*)d_in[3];
  const int* p_len = (const int*)d_in[4];
  const int* ng_len = (const int*)d_in[5];
  const float* w_ih = (const float*)d_in[6];
  const float* w_hh = (const float*)d_in[7];
  const float* b_ih = (const float*)d_in[8];
  const float* b_hh = (const float*)d_in[9];
  const float* lookup_w = (const float*)d_in[10];
  const float* lookup_b = (const float*)d_in[11];
  const float* posres_w = (const float*)d_in[12];
  const float* posres_b = (const float*)d_in[13];
  const float* attn_in_w = (const float*)d_in[14];
  const float* attn_in_b = (const float*)d_in[15];
  const float* attn_out_w = (const float*)d_in[16];
  const float* attn_out_b = (const float*)d_in[17];
  const float* gamma_p = (const float*)d_in[18];
  float* out = (float*)d_out;

  float* coef = (float*)d_ws;      // 5*384 = 1920 floats (pad to 2048)
  float* Mh = coef + 2048;         // 16*25 = 400 floats (pad to 512)
  float* ohat = Mh + 512;          // 3*32*16*8 = 12288 floats
  float* cemb = ohat + 12288;      // 3*32*128  = 12288 floats

  hipLaunchKernelGGL(coef_kernel, dim3(1), dim3(512), 0, stream, attn_in_w,
                     attn_in_b, lookup_w, lookup_b, posres_w, posres_b, coef, Mh);
  hipLaunchKernelGGL(fused_kernel, dim3(NGRU + NATT), dim3(512), 0, stream, a_in,
                     p_in, ng_in, a_len, p_len, ng_len, w_ih, w_hh, b_ih, b_hh,
                     coef, Mh, cemb, ohat);
  hipLaunchKernelGGL(finalize_kernel, dim3(96), dim3(128), 0, stream, attn_out_w,
                     attn_out_b, ohat, cemb, gamma_p, out);
  hipLaunchKernelGGL(dist_kernel, dim3(1), dim3(64), 0, stream, out);
}

// Round 13
// 341.018 us; speedup vs baseline: 1.1875x; 1.1875x over previous
//
#include <hip/hip_runtime.h>
#include <math.h>

#define BB 32
#define TT 512
#define EE 128
#define NHH 16
#define HDD 8
#define G3 384
#define NGRU 96
#define NATT 192

typedef __attribute__((ext_vector_type(2))) _Float16 half2_t;
typedef __attribute__((ext_vector_type(8))) _Float16 half8_t;

__device__ __forceinline__ float exp2_(float x) {
#if __has_builtin(__builtin_amdgcn_exp2f)
  return __builtin_amdgcn_exp2f(x);
#else
  return exp2f(x);
#endif
}

__device__ __forceinline__ float fdot2_(half2_t a, half2_t b, float c) {
#if __has_builtin(__builtin_amdgcn_fdot2)
  return __builtin_amdgcn_fdot2(a, b, c, false);
#else
  return fmaf((float)a[0], (float)b[0], fmaf((float)a[1], (float)b[1], c));
#endif
}

// K0: fold lookup/posres/attn_in into coef[5][384] and per-head 5x5 M (scaled).
__global__ __launch_bounds__(512) void coef_kernel(
    const float* __restrict__ attn_in_w, const float* __restrict__ attn_in_b,
    const float* __restrict__ lookup_w, const float* __restrict__ lookup_b,
    const float* __restrict__ posres_w, const float* __restrict__ posres_b,
    float* __restrict__ coef, float* __restrict__ Mh) {
  int j = threadIdx.x;
  __shared__ float cL[5][G3];
  if (j < G3) {
    float u0 = 0.f, u1 = 0.f, cs = 0.f, cc = 0.f, cb = 0.f;
    const float* wrow = attn_in_w + j * EE;
    for (int e = 0; e < EE; ++e) {
      float w = wrow[e];
      float pw0 = posres_w[e * 2], pw1 = posres_w[e * 2 + 1];
      u0 += w * (lookup_w[e * 2] + pw0);
      u1 += w * (lookup_w[e * 2 + 1] + pw1);
      cs += w * pw0;
      cc += w * pw1;
      cb += w * (lookup_b[e] + posres_b[e]);
    }
    cb += attn_in_b[j];
    coef[0 * G3 + j] = u0;
    coef[1 * G3 + j] = u1;
    coef[2 * G3 + j] = cs;
    coef[3 * G3 + j] = cc;
    coef[4 * G3 + j] = cb;
    cL[0][j] = u0;
    cL[1][j] = u1;
    cL[2][j] = cs;
    cL[3][j] = cc;
    cL[4][j] = cb;
  }
  __syncthreads();
  if (j < NHH * 25) {
    int h = j / 25;
    int ij = j % 25;
    int i = ij / 5, jj = ij % 5;
    const float SCL = 0.35355339059327373f * 1.4426950408889634f;
    float acc = 0.f;
#pragma unroll
    for (int d = 0; d < HDD; ++d)
      acc += cL[i][h * HDD + d] * cL[jj][EE + h * HDD + d];
    Mh[h * 25 + ij] = acc * SCL;
  }
}

// Merged kernel: blocks [0,96) = GRU (one per (s,b), 512 thr, 4-lane groups);
// blocks [96,96+192) = attention (wave = head).
__global__ __launch_bounds__(512, 1) void fused_kernel(
    const float* __restrict__ in0, const float* __restrict__ in1,
    const float* __restrict__ in2, const int* __restrict__ len0,
    const int* __restrict__ len1, const int* __restrict__ len2,
    const float* __restrict__ w_ih, const float* __restrict__ w_hh,
    const float* __restrict__ b_ih, const float* __restrict__ b_hh,
    const float* __restrict__ coef, const float* __restrict__ Mh,
    float* __restrict__ coor_embs, float* __restrict__ ohat) {
  __shared__ __align__(16) unsigned char smem[8192];
  int tid = threadIdx.x;
  if (blockIdx.x < NGRU) {
    // ---------------- GRU: 4-lane groups, f16 weights pinned in-loop ---------
    const float L2E = 1.4426950408889634f;
    const float L2E2 = 2.8853900817779268f;
    int blk = blockIdx.x;
    int s = blk >> 5;
    int b = blk & 31;
    const float* inp = (s == 0) ? in0 : (s == 1) ? in1 : in2;
    const int* lenp = (s == 0) ? len0 : (s == 1) ? len1 : len2;
    int len = lenp[b];
    int e = tid >> 2;   // h element / gate-triple index 0..127
    int kp = tid & 3;   // k-slice 0..3 (32 cols each)

    _Float16* hbh = (_Float16*)smem;          // [2][128]
    float* xst = (float*)(smem + 512);        // [512][2]

    {
      float4 v = *(const float4*)(inp + ((size_t)b * TT + tid) * 4);
      xst[tid * 2] = v.x;
      xst[tid * 2 + 1] = v.y;
    }
    if (tid < EE) hbh[tid] = (_Float16)0.0f;

    int rr = e, rz = e + 128, rn = e + 256;
    // pack 32-col slices, folding log2e (r,z) / 2*log2e (n) into the weights
    half2_t wr[16], wz[16], wn[16];
    {
      const float4* pr = (const float4*)(w_hh + (size_t)rr * EE + 32 * kp);
      const float4* pz = (const float4*)(w_hh + (size_t)rz * EE + 32 * kp);
      const float4* pn = (const float4*)(w_hh + (size_t)rn * EE + 32 * kp);
#pragma unroll
      for (int i = 0; i < 8; ++i) {
        float4 a = pr[i];
        wr[2 * i][0] = (_Float16)(a.x * L2E); wr[2 * i][1] = (_Float16)(a.y * L2E);
        wr[2 * i + 1][0] = (_Float16)(a.z * L2E); wr[2 * i + 1][1] = (_Float16)(a.w * L2E);
        float4 c = pz[i];
        wz[2 * i][0] = (_Float16)(c.x * L2E); wz[2 * i][1] = (_Float16)(c.y * L2E);
        wz[2 * i + 1][0] = (_Float16)(c.z * L2E); wz[2 * i + 1][1] = (_Float16)(c.w * L2E);
        float4 d = pn[i];
        wn[2 * i][0] = (_Float16)(d.x * L2E2); wn[2 * i][1] = (_Float16)(d.y * L2E2);
        wn[2 * i + 1][0] = (_Float16)(d.z * L2E2); wn[2 * i + 1][1] = (_Float16)(d.w * L2E2);
      }
    }
    float br = (b_ih[rr] + b_hh[rr]) * L2E;
    float bz = (b_ih[rz] + b_hh[rz]) * L2E;
    float bn = b_ih[rn] * L2E2;
    float bhn = b_hh[rn] * L2E2;
    float wir0 = w_ih[rr * 2] * L2E, wir1 = w_ih[rr * 2 + 1] * L2E;
    float wiz0 = w_ih[rz * 2] * L2E, wiz1 = w_ih[rz * 2 + 1] * L2E;
    float win0 = w_ih[rn * 2] * L2E2, win1 = w_ih[rn * 2 + 1] * L2E2;

    float hold = 0.0f;
    __syncthreads();

    int cur = 0;
#pragma unroll 1
    for (int t = 0; t < len; ++t) {
      // loop-carry the weights through opaque asm: remat is now illegal, the
      // allocator MUST keep all 48 half2 in VGPRs.
      asm volatile("" : "+v"(wr[0]), "+v"(wr[1]), "+v"(wr[2]), "+v"(wr[3]),
                        "+v"(wr[4]), "+v"(wr[5]), "+v"(wr[6]), "+v"(wr[7]),
                        "+v"(wr[8]), "+v"(wr[9]), "+v"(wr[10]), "+v"(wr[11]),
                        "+v"(wr[12]), "+v"(wr[13]), "+v"(wr[14]), "+v"(wr[15]));
      asm volatile("" : "+v"(wz[0]), "+v"(wz[1]), "+v"(wz[2]), "+v"(wz[3]),
                        "+v"(wz[4]), "+v"(wz[5]), "+v"(wz[6]), "+v"(wz[7]),
                        "+v"(wz[8]), "+v"(wz[9]), "+v"(wz[10]), "+v"(wz[11]),
                        "+v"(wz[12]), "+v"(wz[13]), "+v"(wz[14]), "+v"(wz[15]));
      asm volatile("" : "+v"(wn[0]), "+v"(wn[1]), "+v"(wn[2]), "+v"(wn[3]),
                        "+v"(wn[4]), "+v"(wn[5]), "+v"(wn[6]), "+v"(wn[7]),
                        "+v"(wn[8]), "+v"(wn[9]), "+v"(wn[10]), "+v"(wn[11]),
                        "+v"(wn[12]), "+v"(wn[13]), "+v"(wn[14]), "+v"(wn[15]));

      // 32 h-halfs via 4 broadcast b128 reads (16 lanes/addr: free)
      const half8_t* hp = (const half8_t*)(hbh + cur * EE + 32 * kp);
      half8_t H0 = hp[0], H1 = hp[1], H2 = hp[2], H3 = hp[3];
      const half2_t* c0 = (const half2_t*)&H0;
      const half2_t* c1 = (const half2_t*)&H1;
      const half2_t* c2 = (const half2_t*)&H2;
      const half2_t* c3 = (const half2_t*)&H3;
      float x0 = xst[t * 2], x1 = xst[t * 2 + 1];

      float ar0 = 0.f, ar1 = 0.f, az0 = 0.f, az1 = 0.f, an0 = 0.f, an1 = 0.f;
#pragma unroll
      for (int jj = 0; jj < 4; ++jj) {
        ar0 = fdot2_(wr[jj], c0[jj], ar0);
        az0 = fdot2_(wz[jj], c0[jj], az0);
        an0 = fdot2_(wn[jj], c0[jj], an0);
        ar1 = fdot2_(wr[4 + jj], c1[jj], ar1);
        az1 = fdot2_(wz[4 + jj], c1[jj], az1);
        an1 = fdot2_(wn[4 + jj], c1[jj], an1);
        ar0 = fdot2_(wr[8 + jj], c2[jj], ar0);
        az0 = fdot2_(wz[8 + jj], c2[jj], az0);
        an0 = fdot2_(wn[8 + jj], c2[jj], an0);
        ar1 = fdot2_(wr[12 + jj], c3[jj], ar1);
        az1 = fdot2_(wz[12 + jj], c3[jj], az1);
        an1 = fdot2_(wn[12 + jj], c3[jj], an1);
      }
      float hr = ar0 + ar1, hz = az0 + az1, hn = an0 + an1;

      // 4-lane group reduce: xor 1,2 are quad-perm DPP (VALU-speed)
      hr += __shfl_xor(hr, 1);
      hz += __shfl_xor(hz, 1);
      hn += __shfl_xor(hn, 1);
      hr += __shfl_xor(hr, 2);
      hz += __shfl_xor(hz, 2);
      hn += __shfl_xor(hn, 2);

      // exp2-native gates (log2e pre-folded)
      float r = __builtin_amdgcn_rcpf(1.0f + exp2_(-(br + wir0 * x0 + wir1 * x1 + hr)));
      float z = __builtin_amdgcn_rcpf(1.0f + exp2_(-(bz + wiz0 * x0 + wiz1 * x1 + hz)));
      float targ2 = bn + win0 * x0 + win1 * x1 + r * (bhn + hn);  // = 2*log2e*targ
      float n = 1.0f - 2.0f * __builtin_amdgcn_rcpf(exp2_(targ2) + 1.0f);  // tanh
      hold = n + z * (hold - n);
      if (kp == 0) hbh[(cur ^ 1) * EE + e] = (_Float16)hold;
      __syncthreads();
      cur ^= 1;
    }
    if (kp == 0) coor_embs[(size_t)blk * EE + e] = hold;
  } else {
    // ---------------- Attention (rank-5, q-register-tiled, wave=head) --------
    int a = blockIdx.x - NGRU;  // 0..191: (s, b, head-group)
    int s = a / 64;
    int rem = a - s * 64;
    int b = rem >> 1;
    int hg = rem & 1;
    const float* inp = (s == 0) ? in0 : (s == 1) ? in1 : in2;
    int wave = tid >> 6;
    int lane = tid & 63;
    int h = hg * 8 + wave;

    float4* phiL = (float4*)smem;  // [512]

    {
      int t = tid;
      float ft = (float)t;
      float st = sinf(ft);
      float ct = cosf(ft);
      float4 g = *(const float4*)(inp + ((size_t)b * TT + t) * 4);
      phiL[t] = make_float4(g.z, g.w, st, ct);
    }

    float M[25];
#pragma unroll
    for (int i = 0; i < 25; ++i) M[i] = Mh[h * 25 + i];
    __syncthreads();

    float4 p[8];
#pragma unroll
    for (int j = 0; j < 8; ++j) p[j] = phiL[lane + 64 * j];

    float Z[8];
    float N0[8], N1[8], N2[8], N3[8];
#pragma unroll
    for (int j = 0; j < 8; ++j) {
      Z[j] = 0.f; N0[j] = 0.f; N1[j] = 0.f; N2[j] = 0.f; N3[j] = 0.f;
    }

#pragma unroll 1
    for (int k = 0; k < TT; ++k) {
      float4 f = phiL[k];
      float m0 = fmaf(M[0], f.x, fmaf(M[1], f.y, fmaf(M[2], f.z, fmaf(M[3], f.w, M[4]))));
      float m1 = fmaf(M[5], f.x, fmaf(M[6], f.y, fmaf(M[7], f.z, fmaf(M[8], f.w, M[9]))));
      float m2 = fmaf(M[10], f.x, fmaf(M[11], f.y, fmaf(M[12], f.z, fmaf(M[13], f.w, M[14]))));
      float m3 = fmaf(M[15], f.x, fmaf(M[16], f.y, fmaf(M[17], f.z, fmaf(M[18], f.w, M[19]))));
      float m4 = fmaf(M[20], f.x, fmaf(M[21], f.y, fmaf(M[22], f.z, fmaf(M[23], f.w, M[24]))));
#pragma unroll
      for (int j = 0; j < 8; ++j) {
        float e0 = exp2_(fmaf(p[j].x, m0, fmaf(p[j].y, m1, fmaf(p[j].z, m2, fmaf(p[j].w, m3, m4)))));
        Z[j] += e0;
        N0[j] = fmaf(e0, f.x, N0[j]);
        N1[j] = fmaf(e0, f.y, N1[j]);
        N2[j] = fmaf(e0, f.z, N2[j]);
        N3[j] = fmaf(e0, f.w, N3[j]);
      }
    }

    float od0 = 0.f, od1 = 0.f, od2 = 0.f, od3 = 0.f;
#pragma unroll
    for (int j = 0; j < 8; ++j) {
      float rz = __builtin_amdgcn_rcpf(Z[j] * (float)TT);
      od0 = fmaf(N0[j], rz, od0);
      od1 = fmaf(N1[j], rz, od1);
      od2 = fmaf(N2[j], rz, od2);
      od3 = fmaf(N3[j], rz, od3);
    }
#pragma unroll
    for (int off = 32; off >= 1; off >>= 1) {
      od0 += __shfl_xor(od0, off, 64);
      od1 += __shfl_xor(od1, off, 64);
      od2 += __shfl_xor(od2, off, 64);
      od3 += __shfl_xor(od3, off, 64);
    }
    if (lane < HDD) {
      int jv = 2 * EE + h * HDD + lane;
      float o = coef[jv] * od0 + coef[G3 + jv] * od1 + coef[2 * G3 + jv] * od2 +
                coef[3 * G3 + jv] * od3 + coef[4 * G3 + jv];  // phi4 == 1 exactly
      int abk = s * 512 + b * 16 + h;
      ohat[(size_t)abk * HDD + lane] = o;
    }
  }
}

// K3: grid_emb = ohat @ out_w.T + out_b ; out = gamma*coor + (1-gamma)*grid
__global__ __launch_bounds__(128) void finalize_kernel(
    const float* __restrict__ attn_out_w, const float* __restrict__ attn_out_b,
    const float* __restrict__ ohat, const float* __restrict__ coor_embs,
    const float* __restrict__ gamma_p, float* __restrict__ out) {
  int blk = blockIdx.x;  // s*32 + b
  int e = threadIdx.x;
  __shared__ float ov[EE];
  ov[e] = ohat[(size_t)blk * EE + e];
  __syncthreads();
  float acc = attn_out_b[e];
  const float* wrow = attn_out_w + (size_t)e * EE;
#pragma unroll 8
  for (int f = 0; f < EE; ++f) acc += wrow[f] * ov[f];
  float g = gamma_p[0];
  out[(size_t)blk * EE + e] = g * coor_embs[(size_t)blk * EE + e] + (1.0f - g) * acc;
}

// K4: pos/neg distances from the embeddings already in d_out
__global__ void dist_kernel(float* __restrict__ out) {
  int i = threadIdx.x;  // 64 threads
  int b = i & 31;
  int neg = i >> 5;
  const float* a = out + (size_t)b * EE;
  const float* x = out + (size_t)(1 + neg) * BB * EE + (size_t)b * EE;
  float sum = 0.f;
  for (int e = 0; e < EE; ++e) {
    float d = a[e] - x[e] + 1e-6f;
    sum += d * d;
  }
  out[3 * BB * EE + neg * BB + b] = expf(-sqrtf(sum));
}

extern "C" void kernel_launch(void* const* d_in, const int* in_sizes, int n_in,
                              void* d_out, int out_size, void* d_ws, size_t ws_size,
                              hipStream_t stream) {
  const float* a_in = (const float*)d_in[0];
  const float* p_in = (const float*)d_in[1];
  const float* ng_in = (const float*)d_in[2];
  const int* a_len = (const int*)d_in[3];
  const int* p_len = (const int*)d_in[4];
  const int* ng_len = (const int*)d_in[5];
  const float* w_ih = (const float*)d_in[6];
  const float* w_hh = (const float*)d_in[7];
  const float* b_ih = (const float*)d_in[8];
  const float* b_hh = (const float*)d_in[9];
  const float* lookup_w = (const float*)d_in[10];
  const float* lookup_b = (const float*)d_in[11];
  const float* posres_w = (const float*)d_in[12];
  const float* posres_b = (const float*)d_in[13];
  const float* attn_in_w = (const float*)d_in[14];
  const float* attn_in_b = (const float*)d_in[15];
  const float* attn_out_w = (const float*)d_in[16];
  const float* attn_out_b = (const float*)d_in[17];
  const float* gamma_p = (const float*)d_in[18];
  float* out = (float*)d_out;

  float* coef = (float*)d_ws;      // 5*384 = 1920 floats (pad to 2048)
  float* Mh = coef + 2048;         // 16*25 = 400 floats (pad to 512)
  float* ohat = Mh + 512;          // 3*32*16*8 = 12288 floats
  float* cemb = ohat + 12288;      // 3*32*128  = 12288 floats

  hipLaunchKernelGGL(coef_kernel, dim3(1), dim3(512), 0, stream, attn_in_w,
                     attn_in_b, lookup_w, lookup_b, posres_w, posres_b, coef, Mh);
  hipLaunchKernelGGL(fused_kernel, dim3(NGRU + NATT), dim3(512), 0, stream, a_in,
                     p_in, ng_in, a_len, p_len, ng_len, w_ih, w_hh, b_ih, b_hh,
                     coef, Mh, cemb, ohat);
  hipLaunchKernelGGL(finalize_kernel, dim3(96), dim3(128), 0, stream, attn_out_w,
                     attn_out_b, ohat, cemb, gamma_p, out);
  hipLaunchKernelGGL(dist_kernel, dim3(1), dim3(64), 0, stream, out);
}